// Round 1
// baseline (289.214 us; speedup 1.0000x reference)
//
#include <hip/hip_runtime.h>
#include <math.h>

// x:    [B=8, C=4, H=256, W=256] f32
// filt: [B, C*25, H, W]          f32
// out:  [B, 1, H, W]             f32
// out[b,h,w] = tanh( sum_{c,p} x_pad[b,c,h+p/5-2, w+p%5-2] * filt[b,c*25+p,h,w] )
//
// filt is 209.7 MB read-once => HBM roofline ~35 us. Previous version (276 us)
// was latency-bound: 16B register loads with fmaf consumers kept only ~2-4
// loads in flight/wave. This version stages filt via async global_load_lds
// (1 KB DMA per instruction, no VGPR landing), double-buffered over di with
// counted vmcnt waits, so each wave always has >=5 KB in flight.
#define Hd 256
#define Wd 256
#define Cc 4
#define KK 5

typedef float v4f __attribute__((ext_vector_type(4)));

// 16-byte-per-lane async global->LDS DMA. LDS dest = wave-uniform base + lane*16.
#define GLD16(gaddr, laddr)                                                          \
    __builtin_amdgcn_global_load_lds(                                                \
        (const __attribute__((address_space(1))) void*)(gaddr),                      \
        (__attribute__((address_space(3))) void*)(laddr), 16, 0, 0)

// Stage 5 filter planes (one di row) for this wave's channel: 5 async 1 KB DMAs.
// g0 already includes this lane's +w0 offset; l0 is the wave-uniform LDS row base.
__device__ __forceinline__ void stage_rows(const float* __restrict__ g0, float* l0) {
    const size_t HW = (size_t)Hd * Wd;
#pragma unroll
    for (int dj = 0; dj < KK; ++dj) {
        GLD16(g0 + (size_t)dj * HW, l0 + dj * Wd);
    }
}

__global__ __launch_bounds__(256, 4) void dynf_kernel(const float* __restrict__ x,
                                                      const float* __restrict__ filt,
                                                      float* __restrict__ out) {
    // Block = one (b,h) output row. Wave = one input channel c. Lane = 4-pixel group.
    const int bh   = blockIdx.x;            // [0, 2048)
    const int b    = bh >> 8;
    const int h    = bh & 255;
    const int c    = threadIdx.x >> 6;      // wave id = channel (wave-uniform)
    const int lane = threadIdx.x & 63;
    const int w0   = lane << 2;

    const size_t HW = (size_t)Hd * Wd;

    // Double-buffered filt staging: [buf][channel][dj][256 floats] = 40 KB total
    // => exactly 4 blocks/CU (160 KB LDS). Each wave touches only its own [c] slab,
    // so no __syncthreads needed in the main loop — per-wave vmcnt suffices.
    __shared__ float lds[2][Cc][KK][Wd];

    const float* xc = x + ((size_t)b * Cc + c) * HW;
    // filt base for (b, c, p=0), row h, this lane's 16B chunk:
    const float* fb = filt + ((size_t)b * (Cc * KK * KK) + (size_t)c * (KK * KK)) * HW
                      + (size_t)h * Wd + w0;
    float* lbase = &lds[0][0][0][0];
    float* lc0 = lbase + (size_t)c * (KK * Wd);                    // buf0, channel c
    float* lc1 = lbase + (size_t)Cc * (KK * Wd) + (size_t)c * (KK * Wd); // buf1, chan c

    // ---- Prologue 1: x window rows into registers (zero for out-of-bounds rows).
    // Hoisting ALL x loads here keeps the steady-state loop free of non-staging
    // VMEM ops, so the manual vmcnt counting below is sound.
    float xrow[KK][8];
    const v4f vzero = {0.f, 0.f, 0.f, 0.f};
#pragma unroll
    for (int di = 0; di < KK; ++di) {
        const int hh = h + di - 2;
        if (hh >= 0 && hh < Hd) {
            const float* xr = xc + (size_t)hh * Wd;
            v4f left  = *(const v4f*)(xr + (w0 ? (w0 - 4) : 0));
            v4f mid   = *(const v4f*)(xr + w0);
            v4f right = *(const v4f*)(xr + ((w0 + 4 < Wd) ? (w0 + 4) : 0));
            if (w0 == 0)      left  = vzero;
            if (w0 + 4 >= Wd) right = vzero;
            xrow[di][0] = left.z;  xrow[di][1] = left.w;
            xrow[di][2] = mid.x;   xrow[di][3] = mid.y;
            xrow[di][4] = mid.z;   xrow[di][5] = mid.w;
            xrow[di][6] = right.x; xrow[di][7] = right.y;
        } else {
#pragma unroll
            for (int j = 0; j < 8; ++j) xrow[di][j] = 0.f;
        }
    }

    // ---- Prologue 2: stage di=0 into buf0, di=1 into buf1 (10 DMAs in flight).
    // Staging is unconditional (edge rows multiply by xrow==0) to keep vmcnt
    // arithmetic uniform; costs ~0.5% extra traffic on 8/256 rows.
    stage_rows(fb, lc0);
    asm volatile("" ::: "memory");   // pin DMA program order
    stage_rows(fb + (size_t)KK * HW, lc1);
    asm volatile("" ::: "memory");

    float a0 = 0.f, a1 = 0.f, a2 = 0.f, a3 = 0.f;

#pragma unroll
    for (int di = 0; di < KK; ++di) {
        // Counted wait: the 5 newest outstanding DMAs belong to the NEXT buffer;
        // everything older (current buffer + any prologue x loads) is complete.
        if (di < KK - 1) {
            asm volatile("s_waitcnt vmcnt(5)" ::: "memory");
        } else {
            asm volatile("s_waitcnt vmcnt(0)" ::: "memory");
        }

        const float* lsrc = (di & 1) ? lc1 : lc0;
#pragma unroll
        for (int dj = 0; dj < KK; ++dj) {
            v4f f = *(const v4f*)(lsrc + dj * Wd + w0);
            a0 = fmaf(xrow[di][dj + 0], f.x, a0);
            a1 = fmaf(xrow[di][dj + 1], f.y, a1);
            a2 = fmaf(xrow[di][dj + 2], f.z, a2);
            a3 = fmaf(xrow[di][dj + 3], f.w, a3);
        }

        if (di + 2 < KK) {
            // Drain LDS reads before the DMA can overwrite this buffer, then
            // issue next-next stage into the buffer we just finished reading.
            asm volatile("s_waitcnt lgkmcnt(0)" ::: "memory");
            stage_rows(fb + (size_t)(di + 2) * KK * HW, (di & 1) ? lc1 : lc0);
            asm volatile("" ::: "memory");
        }
    }

    // ---- Cross-wave channel reduction. All DMA drained (vmcnt(0) at di=4),
    // and the barrier makes buf0 reuse as the reduction scratch safe.
    __syncthreads();
    v4f* red = (v4f*)lbase;
    v4f acc;
    acc.x = a0; acc.y = a1; acc.z = a2; acc.w = a3;
    red[(size_t)c * 64 + lane] = acc;
    __syncthreads();

    if (c == 0) {
        v4f s = red[lane] + red[64 + lane] + red[128 + lane] + red[192 + lane];
        v4f o;
        o.x = tanhf(s.x); o.y = tanhf(s.y); o.z = tanhf(s.z); o.w = tanhf(s.w);
        __builtin_nontemporal_store(o, (v4f*)(out + (size_t)b * HW + (size_t)h * Wd + w0));
    }
}

extern "C" void kernel_launch(void* const* d_in, const int* in_sizes, int n_in,
                              void* d_out, int out_size, void* d_ws, size_t ws_size,
                              hipStream_t stream) {
    const float* x    = (const float*)d_in[0];   // [8,4,256,256]
    const float* filt = (const float*)d_in[1];   // [8,100,256,256]
    float* out        = (float*)d_out;           // [8,1,256,256]

    const int grid  = 8 * 256;   // one block per (b,h) row
    const int block = 256;       // 4 waves = 4 channels
    dynf_kernel<<<grid, block, 0, stream>>>(x, filt, out);
}